// Round 13
// baseline (116.753 us; speedup 1.0000x reference)
//
#include <hip/hip_runtime.h>
#include <hip/hip_bf16.h>
#include <hip/hip_fp8.h>
#include <math.h>

#define BROWS 4096
#define DIM   512
#define YEMB_B 2097152   // 4096*512 bytes, offset of emb rows in Yq (fp8)
#define TSTRIDE 63       // tile stride (tiles are 64 wide, overlap by 1)
#define NT 65            // tiles per dim; triangle blocks = 65*66/2 = 2145

typedef float f32x4 __attribute__((ext_vector_type(4)));

// ---------------------------------------------------------------------------
// prep4: wave-per-row, no barriers. 8192 rows (low then emb), 4 rows/block.
// L2-normalize -> fp8 e4m3 row in Yq; s=sum(y^2), r=sum(y) from f32 y.
// (verified R12: absmax 0.0 vs threshold)
// ---------------------------------------------------------------------------
__global__ __launch_bounds__(256) void prep4_kernel(
    const float* __restrict__ low, const float* __restrict__ emb,
    unsigned char* __restrict__ Yq,
    float* __restrict__ s_l, float* __restrict__ r_l,
    float* __restrict__ s_e, float* __restrict__ r_e,
    float* __restrict__ out) {
  const int tid = threadIdx.x;
  const int lane = tid & 63, wid = tid >> 6;
  const int rid = blockIdx.x * 4 + wid;          // 0..8191
  if (blockIdx.x == 0 && tid == 0) out[0] = 0.f;

  const bool is_low = (rid < BROWS);
  const int row = is_low ? rid : rid - BROWS;
  const float* x = (is_low ? low : emb) + (size_t)row * DIM;

  const float4 v0 = ((const float4*)x)[lane * 2];
  const float4 v1 = ((const float4*)x)[lane * 2 + 1];

  float ss = v0.x * v0.x + v0.y * v0.y + v0.z * v0.z + v0.w * v0.w +
             v1.x * v1.x + v1.y * v1.y + v1.z * v1.z + v1.w * v1.w;
#pragma unroll
  for (int o = 1; o < 64; o <<= 1) ss += __shfl_xor(ss, o, 64);
  const float inv = 1.0f / fmaxf(sqrtf(ss), 1e-12f);

  float y[8] = {v0.x * inv, v0.y * inv, v0.z * inv, v0.w * inv,
                v1.x * inv, v1.y * inv, v1.z * inv, v1.w * inv};

  union { unsigned char b[8]; unsigned long long u; } pk;
  float sv = 0.f, rv = 0.f;
#pragma unroll
  for (int i = 0; i < 8; ++i) {
    pk.b[i] = __hip_fp8_e4m3(y[i]).__x;   // OCP e4m3fn, HW RNE
    sv += y[i] * y[i];
    rv += y[i];
  }
  ((unsigned long long*)(Yq + (size_t)rid * 512))[lane] = pk.u;

#pragma unroll
  for (int o = 1; o < 64; o <<= 1) {
    sv += __shfl_xor(sv, o, 64);
    rv += __shfl_xor(rv, o, 64);
  }
  if (lane == 0) {
    (is_low ? s_l : s_e)[row] = sv;
    (is_low ? r_l : r_e)[row] = rv;
  }
}

// ---------------------------------------------------------------------------
// Symmetric fused MFMA kernel, round 13: 64x64 tiles, 4x the block count.
// R12 finding: ~45 us fixed cost = tail quantization (561 blocks at ~2
// generations -> 49-block straggler gen on 19% of CUs) + coarse 8-wave
// granularity. 64x64 tiles cover the triangle TIGHTER (8.8M vs 9.2M cells)
// so total bytes/MFMA are unchanged while blocks -> 2145 (tail ~5%) and
// 4 blocks/CU stagger their barriers.
// Block: 256 thr, 4 waves 2x2 (wr rows 32*wr.., wc cols 32*wc..), wave
// tile 32x32, BOTH matrices live (32 AGPR acc; ~86 regs < (256,4)'s 128).
// K-loop: BK=128 fp8, 4 rounds, 32 KB/round staging (16 KB diag),
// kc^(row&7) swizzle on the GLOBAL side, LDS linear-in-lane.
// MFMA: f32_16x16x32_fp8_fp8 (i64 ops); C/D layout: col=lane&15,
// row=(lane>>4)*4+reg (shape-determined, m121-128).
// Epilogue: R11/R12-proven direct + transposed pair paths scaled to 2x2.
// ---------------------------------------------------------------------------
__global__ __launch_bounds__(256, 4) void fused_sym_kernel(
    const unsigned char* __restrict__ Yq,
    const float* __restrict__ s_l, const float* __restrict__ r_l,
    const float* __restrict__ s_e, const float* __restrict__ r_e,
    float* __restrict__ out) {
  __shared__ __align__(16) unsigned char lds8[32768];  // 32 KB staging
  __shared__ float hand_d[2][32][2];    // dl/de at tile col 32, per wr
  __shared__ float hand_t[2][32][2];    // dl/de at tile row 32 ([wc] slot)
  __shared__ float sred[4];

  // decode upper-triangle block id
  int rem = blockIdx.x, br = 0;
  while (rem >= NT - br) { rem -= NT - br; ++br; }
  const int bc = br + rem;
  const bool diag = (br == bc);

  const int tid = threadIdx.x;
  const int lane = tid & 63;
  const int wid = tid >> 6;          // 0..3
  const int wr = wid >> 1;           // 0..1: rows 32*wr..32*wr+31
  const int wc = wid & 1;            // 0..1: cols 32*wc..32*wc+31
  const int quad = lane >> 4, cpos = lane & 15;
  const int sw = cpos & 7;
  const int r0 = br * TSTRIDE, c0 = bc * TSTRIDE;

  // staging: 2048 slots of 16B; thread owns slot c = tid + 256*s, s=0..7.
  // segs (slots): [0,512) A_low, [512,1024) A_emb,
  //               [1024,1536) B_low, [1536,2048) B_emb.  8 chunks/row.
  // stored K-chunk q holds global chunk q ^ (row&7)  [swizzle].
  int goff[8];   // BYTE offsets into Yq (add k0 per round)
#pragma unroll
  for (int s = 0; s < 8; ++s) {
    const int c = tid + 256 * s;
    const int rloc = (c >> 3) & 63;
    int base;
    if (c < 512)        base = min(r0 + rloc, BROWS - 1) * 512;
    else if (c < 1024)  base = YEMB_B + min(r0 + rloc, BROWS - 1) * 512;
    else if (c < 1536)  base = min(c0 + rloc, BROWS - 1) * 512;
    else                base = YEMB_B + min(c0 + rloc, BROWS - 1) * 512;
    goff[s] = base + (((c & 7) ^ (rloc & 7)) << 4);
  }

  // frag base byte offsets (seg offsets: Alow 0, Aemb 8192, Blow 16384,
  // Bemb 24576; row stride 128 B; u/v stride 16 rows = 2048 B)
  const int abase_l = (32 * wr + cpos) * 128;
  const int abase_e = 8192 + (32 * wr + cpos) * 128;
  const int bbase_l = (diag ? 0 : 16384) + (32 * wc + cpos) * 128;
  const int bbase_e = (diag ? 8192 : 24576) + (32 * wc + cpos) * 128;

  f32x4 accl[2][2], acce[2][2];
#pragma unroll
  for (int u = 0; u < 2; ++u)
#pragma unroll
    for (int v = 0; v < 2; ++v) {
      accl[u][v] = (f32x4)(0.f);
      acce[u][v] = (f32x4)(0.f);
    }

  for (int it = 0; it < 4; ++it) {
    const int k0 = it * 128;
#pragma unroll
    for (int s = 0; s < 8; ++s) {
      if (s < 4 || !diag)   // slots >= 1024 are B segments; skip when diag
        __builtin_amdgcn_global_load_lds(
            (const __attribute__((address_space(1))) void*)(Yq + goff[s] + k0),
            (__attribute__((address_space(3))) void*)(lds8 + (tid + 256 * s) * 16),
            16, 0, 0);
    }
    __syncthreads();

#pragma unroll
    for (int kk = 0; kk < 4; ++kk) {
      const int ch = (((2 * kk + (quad >> 1)) ^ sw) << 4) + (quad & 1) * 8;
      {  // low matrix
        long a[2], b[2];
#pragma unroll
        for (int u = 0; u < 2; ++u) a[u] = *(const long*)(lds8 + abase_l + u * 2048 + ch);
#pragma unroll
        for (int v = 0; v < 2; ++v) b[v] = *(const long*)(lds8 + bbase_l + v * 2048 + ch);
#pragma unroll
        for (int u = 0; u < 2; ++u)
#pragma unroll
          for (int v = 0; v < 2; ++v)
            accl[u][v] = __builtin_amdgcn_mfma_f32_16x16x32_fp8_fp8(
                a[u], b[v], accl[u][v], 0, 0, 0);
      }
      {  // emb matrix
        long a[2], b[2];
#pragma unroll
        for (int u = 0; u < 2; ++u) a[u] = *(const long*)(lds8 + abase_e + u * 2048 + ch);
#pragma unroll
        for (int v = 0; v < 2; ++v) b[v] = *(const long*)(lds8 + bbase_e + v * 2048 + ch);
#pragma unroll
        for (int u = 0; u < 2; ++u)
#pragma unroll
          for (int v = 0; v < 2; ++v)
            acce[u][v] = __builtin_amdgcn_mfma_f32_16x16x32_fp8_fp8(
                a[u], b[v], acce[u][v], 0, 0, 0);
      }
    }
    __syncthreads();
  }

  // ---- transform both accs -> distances in place ----
  const float epst = (float)DIM * 1e-6f * 1e-6f;
#pragma unroll
  for (int v = 0; v < 2; ++v) {
    const int j = min(c0 + 32 * wc + 16 * v + cpos, BROWS - 1);
    const float sjl = s_l[j], rjl = r_l[j];
    const float sje = s_e[j], rje = r_e[j];
#pragma unroll
    for (int u = 0; u < 2; ++u)
#pragma unroll
      for (int r = 0; r < 4; ++r) {
        const int i = min(r0 + 32 * wr + 16 * u + 4 * quad + r, BROWS - 1);
        const float sql = s_l[i] + sjl - 2.f * accl[u][v][r] +
                          2e-6f * (r_l[i] - rjl) + epst;
        accl[u][v][r] = sqrtf(fmaxf(sql, 0.f));
        const float sqe = s_e[i] + sje - 2.f * acce[u][v][r] +
                          2e-6f * (r_e[i] - rje) + epst;
        acce[u][v][r] = sqrtf(fmaxf(sqe, 0.f));
      }
  }
  // now: dl in accl, de in acce

  // ---- publish cross-wave boundary values (dl and de) ----
  if (wc == 1 && cpos == 0) {   // tile col 32 for this wr's 32 rows
#pragma unroll
    for (int u = 0; u < 2; ++u)
#pragma unroll
      for (int r = 0; r < 4; ++r) {
        hand_d[wr][16 * u + 4 * quad + r][0] = accl[u][0][r];
        hand_d[wr][16 * u + 4 * quad + r][1] = acce[u][0][r];
      }
  }
  if (wr == 1 && quad == 0) {   // tile row 32 (u=0,r=0) for this wc's 32 cols
#pragma unroll
    for (int v = 0; v < 2; ++v) {
      hand_t[wc][16 * v + cpos][0] = accl[0][v][0];
      hand_t[wc][16 * v + cpos][1] = acce[0][v][0];
    }
  }
  __syncthreads();

  float sum = 0.f;

  // ---- pass 1: direct terms (i in rows, pair cols j,j+1) ----
  const int srcin = (lane & 48) | ((cpos + 1) & 15);
#pragma unroll
  for (int u = 0; u < 2; ++u)
#pragma unroll
    for (int r = 0; r < 4; ++r) {
      const int trow = 32 * wr + 16 * u + 4 * quad + r;
      const int i = r0 + trow;
      const bool rowok = (trow <= TSTRIDE - 1) && (i <= BROWS - 2);
#pragma unroll
      for (int v = 0; v < 2; ++v) {
        const float dl1 = accl[u][v][r], de1 = acce[u][v][r];
        float dl2 = __shfl(dl1, srcin, 64);
        float de2 = __shfl(de1, srcin, 64);
        if (v < 1) {
          const float dlb = __shfl(accl[u][v + 1][r], lane & 48, 64);
          const float deb = __shfl(acce[u][v + 1][r], lane & 48, 64);
          if (cpos == 15) { dl2 = dlb; de2 = deb; }
        } else if (cpos == 15 && wc == 0) {
          dl2 = hand_d[wr][16 * u + 4 * quad + r][0];
          de2 = hand_d[wr][16 * u + 4 * quad + r][1];
        }
        const int tcol = 32 * wc + 16 * v + cpos;
        const int j = c0 + tcol;
        if (rowok && tcol <= TSTRIDE - 1 && j <= BROWS - 3) {
          const float aa = dl1 - dl2, bb = de1 - de2;
          const float coeff = (float)((aa > 0.f) - (aa < 0.f)) -
                              (float)((bb > 0.f) - (bb < 0.f));
          sum += coeff * (de2 - de1);
        }
      }
    }

  // ---- pass 2: transposed terms (i in cols, pair rows j,j+1), off-diag only ----
  if (!diag) {
#pragma unroll
    for (int u = 0; u < 2; ++u)
#pragma unroll
      for (int v = 0; v < 2; ++v) {
        const int tcol = 32 * wc + 16 * v + cpos;
        const int ii = c0 + tcol;
        const bool colok = (tcol <= TSTRIDE - 1) && (ii <= BROWS - 2);
#pragma unroll
        for (int r = 0; r < 4; ++r) {
          const int trow = 32 * wr + 16 * u + 4 * quad + r;
          const int jj = r0 + trow;
          float dl2, de2;
          if (r < 3) {
            dl2 = accl[u][v][r + 1];
            de2 = acce[u][v][r + 1];
          } else {
            const float dlq = __shfl(accl[u][v][0], (lane + 16) & 63, 64);
            const float deq = __shfl(acce[u][v][0], (lane + 16) & 63, 64);
            const float dlu = __shfl(accl[1][v][0], cpos, 64);
            const float deu = __shfl(acce[1][v][0], cpos, 64);
            if (quad < 3)    { dl2 = dlq; de2 = deq; }
            else if (u == 0) { dl2 = dlu; de2 = deu; }
            else             { dl2 = hand_t[wc][16 * v + cpos][0];  // wr==1 filtered
                               de2 = hand_t[wc][16 * v + cpos][1]; }
          }
          if (colok && trow <= TSTRIDE - 1 && jj <= BROWS - 3) {
            const float dl1 = accl[u][v][r], de1 = acce[u][v][r];
            const float aa = dl1 - dl2, bb = de1 - de2;
            const float coeff = (float)((aa > 0.f) - (aa < 0.f)) -
                                (float)((bb > 0.f) - (bb < 0.f));
            sum += coeff * (de2 - de1);
          }
        }
      }
  }

  // ---- reduce + atomic ----
#pragma unroll
  for (int o = 32; o; o >>= 1) sum += __shfl_down(sum, o, 64);
  if (lane == 0) sred[wid] = sum;
  __syncthreads();
  if (tid == 0) {
    const float scale = 1.0f / ((float)(BROWS - 1) * (float)(BROWS - 2));
    atomicAdd(out, (sred[0] + sred[1] + sred[2] + sred[3]) * scale);
  }
}

// ===========================================================================
extern "C" void kernel_launch(void* const* d_in, const int* in_sizes, int n_in,
                              void* d_out, int out_size, void* d_ws,
                              size_t ws_size, hipStream_t stream) {
  const float* low = (const float*)d_in[0];
  const float* emb = (const float*)d_in[1];
  float* out = (float*)d_out;

  // ws: Yq (2*4096*512 fp8 = 4 MB) then s_l, r_l, s_e, r_e (4096 f32 each)
  unsigned char* Yq = (unsigned char*)d_ws;
  float* s_l = (float*)(Yq + 2 * (size_t)BROWS * DIM);
  float* r_l = s_l + BROWS;
  float* s_e = r_l + BROWS;
  float* r_e = s_e + BROWS;

  prep4_kernel<<<2 * BROWS / 4, 256, 0, stream>>>(low, emb, Yq, s_l, r_l, s_e, r_e, out);
  fused_sym_kernel<<<NT * (NT + 1) / 2, 256, 0, stream>>>(Yq, s_l, r_l, s_e, r_e, out);
}